// Round 2
// baseline (777.711 us; speedup 1.0000x reference)
//
#include <hip/hip_runtime.h>

// Problem constants (B == H == 128, T == 64)
#define TT 64
#define HD 128
#define BB 128
#define G  64      // blocks in persistent loop kernel
#define RPB 2      // rows per block (G*RPB == BB)
#define NT 512     // threads per block

__device__ __forceinline__ float fast_rcp(float x){ return __builtin_amdgcn_rcpf(x); }
__device__ __forceinline__ float fast_tanh(float x){
    float e = __expf(2.f*x);                 // v_exp based; e=inf or 0 at extremes -> +/-1, safe
    return 1.f - 2.f*__builtin_amdgcn_rcpf(e+1.f);
}
__device__ __forceinline__ float fast_sigmoid(float x){
    return __builtin_amdgcn_rcpf(1.f + __expf(-x));
}

// ---------------- precompute kernels ----------------

// Transposes W1 -> W1T[m][k] (m in [0,384)), Whh -> WhhT[k][j], zero flags.
__global__ void k_prep(const float* __restrict__ W1, const float* __restrict__ Whh,
                       float* __restrict__ W1T, float* __restrict__ WhhT,
                       unsigned int* __restrict__ flags){
    int idx = blockIdx.x*blockDim.x + threadIdx.x;
    int stride = gridDim.x*blockDim.x;
    for (int i=idx; i<384*HD; i+=stride){ int m=i>>7, k=i&127; W1T[i] = W1[k*384+m]; }
    for (int i=idx; i<512*HD; i+=stride){ int k=i>>9, j=i&511; WhhT[i] = Whh[j*HD+k]; }
    for (int i=idx; i<TT*G;   i+=stride) flags[i] = 0u;
}

// preE[row][k] = b1[k] + sum_j Xe[row][j] * W1[k][256+j]   (row = b*T+t, 8192 rows)
__global__ void k_pre(const float* __restrict__ Xe, const float* __restrict__ W1T,
                      const float* __restrict__ b1, float* __restrict__ preE){
    __shared__ float sX[2][HD];
    const int tid = threadIdx.x;            // 256
    const int rr = tid>>7, k = tid&127;
    const int row0 = blockIdx.x*32;         // 256 blocks * 32 rows
    const float* wp = W1T + 256*HD + k;     // W1eT[j][k]
    const float bk = b1[k];
    for (int it=0; it<16; ++it){
        int row = row0 + it*2 + rr;
        sX[rr][k] = Xe[row*HD + k];
        __syncthreads();
        float a0=0.f, a1=0.f;
        #pragma unroll 8
        for (int j=0;j<HD;j+=2){
            a0 += sX[rr][j]   * wp[(j)*HD];
            a1 += sX[rr][j+1] * wp[(j+1)*HD];
        }
        preE[row*HD + k] = a0 + a1 + bk;
        __syncthreads();
    }
}

// xtw[t][e] = bfc + sum_b Xt[b][t][e] * Wfc[128+b]
__global__ void k_xtw(const float* __restrict__ Xt, const float* __restrict__ Wfc,
                      const float* __restrict__ bfc, float* __restrict__ xtw){
    const int t = blockIdx.x;       // 64
    const int e = threadIdx.x;      // 128
    float a0=0.f, a1=0.f;
    for (int b=0;b<BB;b+=2){
        a0 += Xt[(b*TT     + t)*HD + e] * Wfc[128+b];
        a1 += Xt[((b+1)*TT + t)*HD + e] * Wfc[129+b];
    }
    xtw[t*HD + e] = a0 + a1 + bfc[0];
}

// ---------------- persistent scan kernel ----------------
// 64 blocks x 512 threads; block g owns rows b0=2g, 2g+1 for attention AND LSTM.
// Only `context` crosses blocks (sc1/LLC ops), one flag barrier per step.
__global__ __launch_bounds__(NT, 1) void k_loop(
    const float* __restrict__ Xe, const float* __restrict__ preE,
    const float* __restrict__ W1T, const float* __restrict__ WhhT,
    const float* __restrict__ xtw,
    const float* __restrict__ W2, const float* __restrict__ b2,
    const float* __restrict__ Wfc,
    const float* __restrict__ Wih, const float* __restrict__ bih,
    const float* __restrict__ bhh,
    const float* __restrict__ Wfin, const float* __restrict__ bfin,
    float* __restrict__ ctxbuf, unsigned int* __restrict__ flags,
    float* __restrict__ out)
{
    __shared__ float sh[RPB][HD], scc[RPB][HD], shW1[RPB][HD];
    __shared__ float sa[RPB][TT], sbeta[RPB][TT];
    __shared__ float sctx[RPB][HD];
    __shared__ float gh[RPB][512];
    __shared__ float red[NT];
    __shared__ float sW2[HD], sWfc[HD], sWih[512], sbihh[512], sWfin[2*HD];
    __shared__ float sy[RPB];
    __shared__ float sb2;

    const int tid = threadIdx.x;
    const int g   = blockIdx.x;
    const int b0  = g*RPB;

    for (int i=tid;i<HD;i+=NT){ sW2[i]=W2[i]; sWfc[i]=Wfc[i]; }
    for (int i=tid;i<512;i+=NT){ sWih[i]=Wih[i]; sbihh[i]=bih[i]+bhh[i]; }
    for (int i=tid;i<2*HD;i+=NT){ sWfin[i]=Wfin[i]; }
    for (int i=tid;i<RPB*HD;i+=NT){ (&sh[0][0])[i]=0.f; (&scc[0][0])[i]=0.f; }
    if (tid==0) sb2 = b2[0];
    __syncthreads();

    for (int t=0;t<TT;t++){
        // ---- hW1[r][k] = sum_m [h;cc][r][m] * W1T[m][k]   (b1 already inside preE) ----
        {
            const int mh = tid>>8;            // m-half: 0 -> h, 1 -> cc
            const int rr = (tid>>7)&1;
            const int k  = tid&127;
            const float* xv = mh ? scc[rr] : sh[rr];
            const float* wp = W1T + (mh*HD)*HD + k;
            float a0=0.f, a1=0.f;
            #pragma unroll 8
            for (int m=0;m<HD;m+=2){
                a0 += xv[m]   * wp[(m)*HD];
                a1 += xv[m+1] * wp[(m+1)*HD];
            }
            red[tid] = a0+a1;
        }
        __syncthreads();
        if (tid<256){
            const int rr = tid>>7, k = tid&127;
            shW1[rr][k] = red[tid] + red[tid+256];
        }
        __syncthreads();

        // ---- scores a[r][t'] = b2 + sum_k W2[k]*tanh(preE + hW1) ----
        {
            const int rr = tid>>8;
            const int rest = tid&255;
            const int tp = rest>>2;           // t' 0..63
            const int kp = rest&3;            // k quarter
            const int k0 = kp*32;
            const float4* pe4 = (const float4*)(preE + ((b0+rr)*TT + tp)*HD + k0);
            float acc=0.f;
            #pragma unroll
            for (int q=0;q<8;q++){
                float4 v = pe4[q];
                int k = k0 + q*4;
                acc += sW2[k+0]*fast_tanh(v.x + shW1[rr][k+0]);
                acc += sW2[k+1]*fast_tanh(v.y + shW1[rr][k+1]);
                acc += sW2[k+2]*fast_tanh(v.z + shW1[rr][k+2]);
                acc += sW2[k+3]*fast_tanh(v.w + shW1[rr][k+3]);
            }
            acc += __shfl_xor(acc,1);
            acc += __shfl_xor(acc,2);
            if (kp==0) sa[rr][tp] = acc + sb2;
        }
        __syncthreads();

        // ---- softmax over t' (one wave per row) ----
        if (tid<2*TT){
            const int rr = tid>>6, l = tid&63;
            float v = sa[rr][l];
            float mx = v;
            #pragma unroll
            for (int d=32;d;d>>=1) mx = fmaxf(mx, __shfl_xor(mx,d));
            float e = __expf(v-mx);
            float s = e;
            #pragma unroll
            for (int d=32;d;d>>=1) s += __shfl_xor(s,d);
            sbeta[rr][l] = e * fast_rcp(s);
        }
        __syncthreads();

        // ---- context[r][e] = sum_t' beta * Xe ----
        {
            const int rr = tid>>8;
            const int rest = tid&255;
            const int tp = rest>>7;           // 0..1 halves of t'
            const int e = rest&127;
            const float* xr = Xe + ((b0+rr)*TT + tp*32)*HD + e;
            float acc=0.f;
            #pragma unroll 8
            for (int q=0;q<32;q++) acc += sbeta[rr][tp*32+q] * xr[q*HD];
            red[tid]=acc;
        }
        __syncthreads();
        if (tid<256){
            const int rr = tid>>7, e = tid&127;
            float c = red[rr*256 + e] + red[rr*256 + 128 + e];
            sctx[rr][e] = c;
            __hip_atomic_store(&ctxbuf[((t&1)*BB + b0+rr)*HD + e], c,
                               __ATOMIC_RELAXED, __HIP_MEMORY_SCOPE_AGENT);
        }
        __syncthreads();   // compiler emits vmcnt(0) before s_barrier -> ctx stores at LLC
        if (tid==0)
            __hip_atomic_store(&flags[t*G + g], 1u, __ATOMIC_RELAXED, __HIP_MEMORY_SCOPE_AGENT);

        // ---- ghh[r][j] = sum_k h[r][k]*Whh[j][k]  (local; overlaps barrier wait) ----
        {
            const float* wp = WhhT + tid;
            float a0=0.f, a1=0.f;
            #pragma unroll 4
            for (int k=0;k<HD;k++){
                float w = wp[k*512];
                a0 += w*sh[0][k];
                a1 += w*sh[1][k];
            }
            gh[0][tid]=a0; gh[1][tid]=a1;
        }

        // ---- wait for all blocks' context ----
        if (tid<G){
            const unsigned int* fp = flags + t*G;
            while (!__all(__hip_atomic_load(&fp[tid], __ATOMIC_RELAXED, __HIP_MEMORY_SCOPE_AGENT) != 0u))
                __builtin_amdgcn_s_sleep(1);
        }
        __syncthreads();

        // ---- y[r] = xtw[t][b0+r] + sum_b' ctx[b'][b0+r]*Wfc[b'] ----
        if (tid<256){
            const int rr = tid>>7, bp = tid&127;
            float c = __hip_atomic_load(&ctxbuf[((t&1)*BB + bp)*HD + (b0+rr)],
                                        __ATOMIC_RELAXED, __HIP_MEMORY_SCOPE_AGENT);
            float p = c * sWfc[bp];
            #pragma unroll
            for (int d=32;d;d>>=1) p += __shfl_xor(p,d);
            if ((tid&63)==0) red[tid>>6]=p;
        }
        __syncthreads();
        if (tid<RPB) sy[tid] = red[2*tid]+red[2*tid+1] + xtw[t*HD + b0+tid];
        __syncthreads();

        // ---- gates + LSTM cell update (PyTorch i,f,g,o order) ----
        if (tid<256){
            const int rr = tid>>7, u = tid&127;
            const float yv = sy[rr];
            float gi = gh[rr][u      ] + yv*sWih[u      ] + sbihh[u      ];
            float gf = gh[rr][128+u  ] + yv*sWih[128+u  ] + sbihh[128+u  ];
            float gg = gh[rr][256+u  ] + yv*sWih[256+u  ] + sbihh[256+u  ];
            float go = gh[rr][384+u  ] + yv*sWih[384+u  ] + sbihh[384+u  ];
            float c2 = fast_sigmoid(gf)*scc[rr][u] + fast_sigmoid(gi)*fast_tanh(gg);
            float h2 = fast_sigmoid(go)*fast_tanh(c2);
            scc[rr][u]=c2; sh[rr][u]=h2;
        }
        __syncthreads();
    }

    // ---- out[b] = bfin + h . Wfin[0:128] + ctx . Wfin[128:256] ----
    if (tid<256){
        const int rr = tid>>7, u = tid&127;
        float p = sh[rr][u]*sWfin[u] + sctx[rr][u]*sWfin[HD+u];
        #pragma unroll
        for (int d=32;d;d>>=1) p += __shfl_xor(p,d);
        if ((tid&63)==0) red[tid>>6]=p;
    }
    __syncthreads();
    if (tid<RPB) out[b0+tid] = red[2*tid]+red[2*tid+1] + bfin[0];
}

// ---------------- launcher ----------------
extern "C" void kernel_launch(void* const* d_in, const int* in_sizes, int n_in,
                              void* d_out, int out_size, void* d_ws, size_t ws_size,
                              hipStream_t stream){
    const float* Xe  = (const float*)d_in[0];
    const float* Xt  = (const float*)d_in[1];
    const float* W1  = (const float*)d_in[2];
    const float* b1  = (const float*)d_in[3];
    const float* W2  = (const float*)d_in[4];
    const float* b2  = (const float*)d_in[5];
    const float* Wfc = (const float*)d_in[6];
    const float* bfc = (const float*)d_in[7];
    const float* Wih = (const float*)d_in[8];
    const float* bih = (const float*)d_in[9];
    const float* Whh = (const float*)d_in[10];
    const float* bhh = (const float*)d_in[11];
    const float* Wfin= (const float*)d_in[12];
    const float* bfin= (const float*)d_in[13];

    float* ws     = (float*)d_ws;
    float* preE   = ws;                               // 128*64*128
    float* W1T    = preE   + (size_t)BB*TT*HD;        // 384*128
    float* WhhT   = W1T    + 384*HD;                  // 512*128 (as [k][j])
    float* xtw    = WhhT   + 512*HD;                  // 64*128
    float* ctxbuf = xtw    + TT*HD;                   // 2*128*128
    unsigned int* flags = (unsigned int*)(ctxbuf + 2*BB*HD);  // 64*64
    float* outp   = (float*)d_out;

    hipLaunchKernelGGL(k_prep, dim3(128), dim3(256), 0, stream, W1, Whh, W1T, WhhT, flags);
    hipLaunchKernelGGL(k_pre,  dim3(256), dim3(256), 0, stream, Xe, W1T, b1, preE);
    hipLaunchKernelGGL(k_xtw,  dim3(64),  dim3(128), 0, stream, Xt, Wfc, bfc, xtw);
    hipLaunchKernelGGL(k_loop, dim3(G),   dim3(NT),  0, stream,
        Xe, preE, W1T, WhhT, xtw, W2, b2, Wfc, Wih, bih, bhh, Wfin, bfin,
        ctxbuf, flags, outp);
}